// Round 14
// baseline (84.761 us; speedup 1.0000x reference)
//
#include <hip/hip_runtime.h>

typedef __bf16 bf16;
typedef float f32x4 __attribute__((ext_vector_type(4)));
typedef bf16 bf16x4 __attribute__((ext_vector_type(4)));
typedef bf16 bf16x8 __attribute__((ext_vector_type(8)));

#define MFMA16(a, b, c) __builtin_amdgcn_mfma_f32_16x16x32_bf16((a), (b), (c), 0, 0, 0)

__device__ __forceinline__ f32x4 zero4() {
    f32x4 z; z[0] = 0.f; z[1] = 0.f; z[2] = 0.f; z[3] = 0.f; return z;
}
__device__ __forceinline__ float max3f(float a, float b, float c) {
    return fmaxf(fmaxf(a, b), c);      // fuses to v_max3_f32
}
// async global -> LDS, 16B/lane. LDS dest = wave-uniform base + lane*16.
__device__ __forceinline__ void gl_lds16(const bf16* g, bf16* l) {
    __builtin_amdgcn_global_load_lds(
        (const __attribute__((address_space(1))) void*)g,
        (__attribute__((address_space(3))) void*)l, 16, 0, 0);
}

// ---------------- fused prep: x f32->bf16 | transpose w_attn | transpose w_proj ----------------
__global__ __launch_bounds__(256)
void prep_k(const float* __restrict__ x, bf16* __restrict__ xb,
            const float* __restrict__ w_attn, bf16* __restrict__ wT,
            const float* __restrict__ w_proj, bf16* __restrict__ wpT)
{
    __shared__ bf16 Ls[64][72];
    const int blk = blockIdx.x;
    const int tid = threadIdx.x;

    if (blk < 2048) {
        const int i = (blk * 256 + tid) * 8;
        const float4 a = *(const float4*)(x + i);
        const float4 b = *(const float4*)(x + i + 4);
        bf16x8 o;
        o[0] = (bf16)a.x; o[1] = (bf16)a.y; o[2] = (bf16)a.z; o[3] = (bf16)a.w;
        o[4] = (bf16)b.x; o[5] = (bf16)b.y; o[6] = (bf16)b.z; o[7] = (bf16)b.w;
        *(bf16x8*)(xb + i) = o;
        return;
    }
    const float* src;
    bf16* dst;
    int K, N, bx, by;
    if (blk < 2816) {
        const int r = blk - 2048;
        src = w_attn; dst = wT; K = 1024; N = 3072;
        bx = r % 48; by = r / 48;
    } else {
        const int r = blk - 2816;
        src = w_proj; dst = wpT; K = 1024; N = 1024;
        bx = r & 15; by = r >> 4;
    }
    const int k0 = by << 6;
    const int n0 = bx << 6;
    #pragma unroll
    for (int it = 0; it < 4; ++it) {
        const int lin = (it << 10) + (tid << 2);
        const int r = lin >> 6, c = lin & 63;
        const float4 v = *(const float4*)(src + (size_t)(k0 + r) * N + n0 + c);
        bf16x4 o; o[0] = (bf16)v.x; o[1] = (bf16)v.y; o[2] = (bf16)v.z; o[3] = (bf16)v.w;
        *(bf16x4*)&Ls[r][c] = o;
    }
    __syncthreads();
    #pragma unroll
    for (int it = 0; it < 2; ++it) {
        const int lin = (it << 11) + (tid << 3);
        const int nn = lin >> 6, kk = lin & 63;
        bf16x8 o;
        #pragma unroll
        for (int j = 0; j < 8; ++j) o[j] = Ls[kk + j][nn];
        *(bf16x8*)(dst + (size_t)(n0 + nn) * K + k0 + kk) = o;
    }
}

// ---------------- bf16 GEMM, B^T input, depth-2 counted-vmcnt pipeline, BK=32 ----------------
// Fully unrolled K-loop: buffer slots, prefetch guards, and global offsets are static.
// MODE 0 (BN=128): scatter q/k packed [bh][t][d] + v transposed+t-permuted [bh][d][t'] via LDS-pack
// MODE 1 (BN=64):  f32 out[M][N] + bias, direct stores
template <int MODE>
__global__ __launch_bounds__(256)
void gemm_bt(const bf16* __restrict__ A, const bf16* __restrict__ Bt,
             const float* __restrict__ bias,
             bf16* __restrict__ qw, bf16* __restrict__ kw, bf16* __restrict__ vw,
             float* __restrict__ outf)
{
    constexpr int BK = 32;
    constexpr int BN = (MODE == 0) ? 128 : 64;
    constexpr int K  = 1024;
    constexpr int N  = (MODE == 0) ? 3072 : 1024;
    constexpr int MF = (MODE == 0) ? 4 : 2;
    constexpr int NF = 4;
    constexpr int AE = 128 * BK;
    constexpr int BE = BN * BK;
    constexpr int nk = K / BK;                   // 32

    __shared__ __align__(16) bf16 smem[3 * (AE + BE)];
    bf16* const Asb = smem;
    bf16* const Bsb = smem + 3 * AE;

    const int tid  = threadIdx.x;
    const int lane = tid & 63;
    const int wid  = tid >> 6;
    const int l16  = lane & 15;
    const int g    = lane >> 4;
    const int wrb  = (MODE == 0) ? ((wid >> 1) << 6) : (wid << 5);
    const int wcb  = (MODE == 0) ? ((wid & 1) << 6) : 0;

    // ---- XCD-aware bijective 2-D swizzle (1-D grid) ----
    const int p   = blockIdx.x;
    const int xcd = p & 7;
    const int r   = p >> 3;
    int by, bx;
    if (MODE == 0) { by = ((xcd >> 1) << 3) + r / 12; bx = (xcd & 1) * 12 + r % 12; }
    else           { by = ((xcd >> 1) << 3) + (r >> 3); bx = ((xcd & 1) << 3) + (r & 7); }
    const int m0 = by << 7;
    const int n0 = bx * BN;

    // staging: 16 rows x 64B per instr; source chunk XOR-preswizzled by (row>>1)&3
    const int srow = lane >> 2;
    const int schk = lane & 3;
    const int rA0 = (wid << 5) + srow;
    const int rA1 = rA0 + 16;
    const int rB0 = wid * (BN / 4) + srow;
    const int rB1 = rB0 + 16;
    const bf16* const pa0 = A  + (size_t)(m0 + rA0) * K + ((schk ^ ((rA0 >> 1) & 3)) << 3);
    const bf16* const pa1 = A  + (size_t)(m0 + rA1) * K + ((schk ^ ((rA1 >> 1) & 3)) << 3);
    const bf16* const pb0 = Bt + (size_t)(n0 + rB0) * K + ((schk ^ ((rB0 >> 1) & 3)) << 3);
    const bf16* const pb1 = Bt + (size_t)(n0 + rB1) * K + ((schk ^ ((rB1 >> 1) & 3)) << 3);
    const int dA0 = (wid << 5) * BK, dA1 = dA0 + 16 * BK;
    const int dB0 = (wid * (BN / 4)) * BK, dB1 = dB0 + 16 * BK;

    // fragment read offsets (elems), swizzle-matched
    int offA[MF], offB[NF];
    #pragma unroll
    for (int mf = 0; mf < MF; ++mf) {
        const int rr = wrb + (mf << 4) + l16;
        offA[mf] = rr * BK + ((g ^ ((rr >> 1) & 3)) << 3);
    }
    #pragma unroll
    for (int nf = 0; nf < NF; ++nf) {
        const int rr = wcb + (nf << 4) + l16;
        offB[nf] = rr * BK + ((g ^ ((rr >> 1) & 3)) << 3);
    }

    f32x4 acc[MF][NF];
    #pragma unroll
    for (int i = 0; i < MF; ++i)
        #pragma unroll
        for (int j = 0; j < NF; ++j) acc[i][j] = zero4();

    auto issue = [&](int t, int s) {
        bf16* const ab = Asb + s * AE;
        bf16* const bb = Bsb + s * BE;
        gl_lds16(pa0 + t * BK, ab + dA0);
        gl_lds16(pa1 + t * BK, ab + dA1);
        gl_lds16(pb0 + t * BK, bb + dB0);
        if constexpr (MODE == 0) gl_lds16(pb1 + t * BK, bb + dB1);
    };

    issue(0, 0);
    issue(1, 1);

    #pragma unroll
    for (int kt = 0; kt < nk; ++kt) {
        if (kt == nk - 1) {
            asm volatile("s_waitcnt vmcnt(0)" ::: "memory");
        } else {
            if constexpr (MODE == 0) asm volatile("s_waitcnt vmcnt(4)" ::: "memory");
            else                     asm volatile("s_waitcnt vmcnt(3)" ::: "memory");
        }
        __builtin_amdgcn_s_barrier();            // tile kt staged for all waves
        if (kt + 2 < nk) issue(kt + 2, (kt + 2) % 3);
        const bf16* const ac = Asb + (kt % 3) * AE;
        const bf16* const bc = Bsb + (kt % 3) * BE;
        bf16x8 af[MF], bfr[NF];
        #pragma unroll
        for (int mf = 0; mf < MF; ++mf) af[mf] = *(const bf16x8*)&ac[offA[mf]];
        #pragma unroll
        for (int nf = 0; nf < NF; ++nf) bfr[nf] = *(const bf16x8*)&bc[offB[nf]];
        __builtin_amdgcn_s_setprio(1);
        #pragma unroll
        for (int mf = 0; mf < MF; ++mf)
            #pragma unroll
            for (int nf = 0; nf < NF; ++nf)
                acc[mf][nf] = MFMA16(af[mf], bfr[nf], acc[mf][nf]);
        __builtin_amdgcn_s_setprio(0);
    }
    __syncthreads();                             // reads done before smem reuse

    if (MODE == 0) {
        // ---- LDS-pack epilogue: 128x128 bf16 tile reusing smem ----
        bf16* const Es = smem;
        const int bq  = m0 >> 10;
        const int tb  = m0 & 1023;
        const int hh0 = (n0 & 1023) >> 6;
        const bool isV = (n0 >= 2048);
        if (isV) {
            #pragma unroll
            for (int mf = 0; mf < MF; ++mf)
                #pragma unroll
                for (int nf = 0; nf < NF; ++nf) {
                    const int nn = wcb + (nf << 4) + l16;
                    const float bs = bias[n0 + nn];
                    bf16x4 pq;
                    #pragma unroll
                    for (int j = 0; j < 4; ++j) pq[j] = (bf16)(acc[mf][nf][j] + bs);
                    // transposed + PV-kmap permuted: t = 32s+16h+4g'+j -> pos 32s+8g'+4h+j
                    const int m = wrb + (mf << 4) + (g << 2);
                    const int pp = ((m >> 5) << 5) + (((m >> 2) & 3) << 3) + (((m >> 4) & 1) << 2);
                    *(bf16x4*)&Es[nn * 128 + pp] = pq;
                }
        } else {
            #pragma unroll
            for (int mf = 0; mf < MF; ++mf)
                #pragma unroll
                for (int nf = 0; nf < NF; ++nf) {
                    const int nn = wcb + (nf << 4) + l16;
                    const float bs = bias[n0 + nn];
                    #pragma unroll
                    for (int j = 0; j < 4; ++j) {
                        const int mm = wrb + (mf << 4) + (g << 2) + j;
                        Es[mm * 128 + nn] = (bf16)(acc[mf][nf][j] + bs);
                    }
                }
        }
        __syncthreads();
        #pragma unroll
        for (int it = 0; it < 8; ++it) {
            const int idx = (it << 8) + tid;
            const int row = idx >> 4, ch = idx & 15;
            const bf16x8 v = *(const bf16x8*)&Es[row * 128 + (ch << 3)];
            if (isV) {
                const int dd = row & 63, hh = hh0 + (row >> 6);
                *(bf16x8*)(vw + ((size_t)((bq << 4) + hh) << 16) + ((size_t)dd << 10)
                           + tb + (ch << 3)) = v;
            } else {
                const int t = tb + row;
                const int cc = ch << 3;
                const int hh = hh0 + (cc >> 6);
                bf16* const dst = (n0 < 1024) ? qw : kw;
                *(bf16x8*)(dst + ((size_t)((bq << 4) + hh) << 16) + ((size_t)t << 6)
                           + (cc & 63)) = v;
            }
        }
    } else {
        #pragma unroll
        for (int mf = 0; mf < MF; ++mf)
            #pragma unroll
            for (int nf = 0; nf < NF; ++nf) {
                const int ng = n0 + wcb + (nf << 4) + l16;
                const float bs = bias[ng];
                #pragma unroll
                for (int j = 0; j < 4; ++j) {
                    const int mg = m0 + wrb + (mf << 4) + (g << 2) + j;
                    outf[(size_t)mg * N + ng] = acc[mf][nf][j] + bs;
                }
            }
    }
}

// ---------------- flash attention: swapped-QK^T, fused dual-q-block kv sweep ----------------
// Q,K [bh][1024][64]; Vt [bh][64][1024 t-permuted]; out att [4096][1024] bf16.
// grid (64, 8): blockIdx.x = bh (same-head blocks land on one XCD).
// Block bx owns q-blocks q1=bx and q2=15-bx over ONE kv sweep kt=0..15-bx.
// TRIPLE-buffered K/V with prefetch distance 2 and counted vmcnt ledger:
//   issue(kt+2) -> vmcnt(8) waits only tile kt's 4 oldest loads; kt+1/kt+2 stay in
//   flight across both barriers. Slot (kt+2)%3 was last read at iter kt-1 (trailing
//   barrier = WAR fence). K and V^T fragments hoisted once, shared by both q-blocks.
__global__ __launch_bounds__(256)
void attn_k(const bf16* __restrict__ Qp, const bf16* __restrict__ Kp,
            const bf16* __restrict__ Vt, bf16* __restrict__ att)
{
    __shared__ __align__(16) bf16 Kls[3 * 64 * 64];
    __shared__ __align__(16) bf16 Vls[3 * 64 * 64];

    const int bh = blockIdx.x;          // 0..63
    const int bx = blockIdx.y;          // 0..7
    const int b  = bh >> 4, h = bh & 15;

    const int tid  = threadIdx.x;
    const int lane = tid & 63;
    const int wid  = tid >> 6;
    const int g    = lane >> 4;
    const int l16  = lane & 15;
    const int g8   = g << 3;

    const size_t hb = (size_t)bh << 16;
    const bf16* Qh = Qp + hb;
    const bf16* Kh = Kp + hb;
    const bf16* Vh = Vt + hb;

    // staging: 8 rows x 128B per instr; source chunk XOR-preswizzled by row&7
    const int srow = lane >> 3;
    const int sswz = ((lane & 7) ^ srow) << 3;
    const int kr0  = (wid << 4) + srow;
    const int kr1  = kr0 + 8;
    const int dst0 = (wid << 4) << 6;
    const int dst1 = ((wid << 4) + 8) << 6;

    // fragment read offsets (elems), swizzle-matched; rows = kv (K) or d (V^T)
    int offKV[2][4];
    #pragma unroll
    for (int ks = 0; ks < 2; ++ks)
        #pragma unroll
        for (int cb = 0; cb < 4; ++cb) {
            const int r = (cb << 4) + l16;
            offKV[ks][cb] = (r << 6) + (((((ks << 2) + g)) ^ (r & 7)) << 3);
        }

    const float QSCALE = 0.125f * 1.44269504f;

    const int q1b = bx;
    const int q2b = 15 - bx;
    const int nkt = q2b;
    const int qloc = (wid << 4) + l16;

    // hoist both Q fragment sets, pre-scaled
    const bf16* qp1 = Qh + ((size_t)((q1b << 6) + qloc) << 6) + g8;
    const bf16* qp2 = Qh + ((size_t)((q2b << 6) + qloc) << 6) + g8;
    bf16x8 q1f0 = *(const bf16x8*)qp1, q1f1 = *(const bf16x8*)(qp1 + 32);
    bf16x8 q2f0 = *(const bf16x8*)qp2, q2f1 = *(const bf16x8*)(qp2 + 32);
    #pragma unroll
    for (int e = 0; e < 8; ++e) {
        q1f0[e] = (bf16)(QSCALE * (float)q1f0[e]);
        q1f1[e] = (bf16)(QSCALE * (float)q1f1[e]);
        q2f0[e] = (bf16)(QSCALE * (float)q2f0[e]);
        q2f1[e] = (bf16)(QSCALE * (float)q2f1[e]);
    }

    f32x4 acc1[4], acc2[4];
    float m1 = -1e30f, l1 = 0.f, m2 = -1e30f, l2 = 0.f;
    #pragma unroll
    for (int i = 0; i < 4; ++i) { acc1[i] = zero4(); acc2[i] = zero4(); }

    // stage tile t into buffer slot s
    auto stage = [&](int t, int s) {
        const int kv = t << 6;
        bf16* const Kn = Kls + s * 4096;
        bf16* const Vn = Vls + s * 4096;
        gl_lds16(Kh + ((size_t)(kv + kr0) << 6) + sswz, Kn + dst0);
        gl_lds16(Kh + ((size_t)(kv + kr1) << 6) + sswz, Kn + dst1);
        gl_lds16(Vh + ((size_t)kr0 << 10) + kv + sswz, Vn + dst0);
        gl_lds16(Vh + ((size_t)kr1 << 10) + kv + sswz, Vn + dst1);
    };

    stage(0, 0);
    stage(1, 1);        // nkt >= 8 always, so tile 1 exists

    for (int kt = 0; kt <= nkt; ++kt) {
        const int slot = kt % 3;
        if (kt + 2 <= nkt) {
            stage(kt + 2, (kt + 2) % 3);
            asm volatile("s_waitcnt vmcnt(8)" ::: "memory");   // tile kt's 4 loads done
        } else if (kt + 1 <= nkt) {
            asm volatile("s_waitcnt vmcnt(4)" ::: "memory");
        } else {
            asm volatile("s_waitcnt vmcnt(0)" ::: "memory");
        }
        __builtin_amdgcn_s_barrier();            // all waves' tile-kt stage visible
        const bf16* Kc = Kls + slot * 4096;
        const bf16* Vc = Vls + slot * 4096;

        // preload K and V^T fragments once (shared by both q-blocks)
        bf16x8 kf[2][4], vf[2][4];
        #pragma unroll
        for (int ks = 0; ks < 2; ++ks)
            #pragma unroll
            for (int cb = 0; cb < 4; ++cb) {
                kf[ks][cb] = *(const bf16x8*)&Kc[offKV[ks][cb]];
                vf[ks][cb] = *(const bf16x8*)&Vc[offKV[ks][cb]];
            }

        // ---- q2 (always active) ----
        {
            f32x4 sacc[4];
            #pragma unroll
            for (int cb = 0; cb < 4; ++cb) sacc[cb] = zero4();
            #pragma unroll
            for (int cb = 0; cb < 4; ++cb) sacc[cb] = MFMA16(kf[0][cb], q2f0, sacc[cb]);
            #pragma unroll
            for (int cb = 0; cb < 4; ++cb) sacc[cb] = MFMA16(kf[1][cb], q2f1, sacc[cb]);
            if (kt == q2b) {
                #pragma unroll
                for (int cb = 0; cb < 4; ++cb)
                    #pragma unroll
                    for (int j = 0; j < 4; ++j)
                        if (((cb << 4) + (g << 2) + j) > qloc) sacc[cb][j] = -1e30f;
            }
            const float t0 = max3f(sacc[0][0], sacc[0][1], sacc[0][2]);
            const float t1 = max3f(sacc[0][3], sacc[1][0], sacc[1][1]);
            const float t2 = max3f(sacc[1][2], sacc[1][3], sacc[2][0]);
            const float t3 = max3f(sacc[2][1], sacc[2][2], sacc[2][3]);
            const float t4 = max3f(sacc[3][0], sacc[3][1], sacc[3][2]);
            float pm = fmaxf(max3f(t0, t1, t2), max3f(t3, t4, sacc[3][3]));
            pm = fmaxf(pm, __shfl_xor(pm, 16));
            pm = fmaxf(pm, __shfl_xor(pm, 32));
            if (__any(pm > m2 + 8.f)) {
                const float mn = fmaxf(m2, pm);
                const float sc = __builtin_amdgcn_exp2f(m2 - mn);
                m2 = mn; l2 *= sc;
                #pragma unroll
                for (int db = 0; db < 4; ++db)
                    #pragma unroll
                    for (int j = 0; j < 4; ++j) acc2[db][j] *= sc;
            }
            float rsum = 0.f;
            #pragma unroll
            for (int cb = 0; cb < 4; ++cb)
                #pragma unroll
                for (int j = 0; j < 4; ++j) {
                    const float pv = __builtin_amdgcn_exp2f(sacc[cb][j] - m2);
                    sacc[cb][j] = pv;
                    rsum += pv;
                }
            rsum += __shfl_xor(rsum, 16);
            rsum += __shfl_xor(rsum, 32);
            l2 += rsum;
            bf16x8 pf0, pf1;
            #pragma unroll
            for (int i = 0; i < 8; ++i) {
                pf0[i] = (bf16)sacc[i >> 2][i & 3];
                pf1[i] = (bf16)sacc[2 + (i >> 2)][i & 3];
            }
            #pragma unroll
            for (int db = 0; db < 4; ++db) acc2[db] = MFMA16(vf[0][db], pf0, acc2[db]);
            #pragma unroll
            for (int db = 0; db < 4; ++db) acc2[db] = MFMA16(vf[1][db], pf1, acc2[db]);
        }

        // ---- q1 (active while kt <= q1b) ----
        if (kt <= q1b) {
            f32x4 sacc[4];
            #pragma unroll
            for (int cb = 0; cb < 4; ++cb) sacc[cb] = zero4();
            #pragma unroll
            for (int cb = 0; cb < 4; ++cb) sacc[cb] = MFMA16(kf[0][cb], q1f0, sacc[cb]);
            #pragma unroll
            for (int cb = 0; cb < 4; ++cb) sacc[cb] = MFMA16(kf[1][cb], q1f1, sacc[cb]);
            if (kt == q1b) {
                #pragma unroll
                for (int cb = 0; cb < 4; ++cb)
                    #pragma unroll
                    for (int j = 0; j < 4; ++j)
                        if (((cb << 4) + (g << 2) + j) > qloc) sacc[cb][j] = -1e30f;
            }
            const float t0 = max3f(sacc[0][0], sacc[0][1], sacc[0][2]);
            const float t1 = max3f(sacc[0][3], sacc[1][0], sacc[1][1]);
            const float t2 = max3f(sacc[1][2], sacc[1][3], sacc[2][0]);
            const float t3 = max3f(sacc[2][1], sacc[2][2], sacc[2][3]);
            const float t4 = max3f(sacc[3][0], sacc[3][1], sacc[3][2]);
            float pm = fmaxf(max3f(t0, t1, t2), max3f(t3, t4, sacc[3][3]));
            pm = fmaxf(pm, __shfl_xor(pm, 16));
            pm = fmaxf(pm, __shfl_xor(pm, 32));
            if (__any(pm > m1 + 8.f)) {
                const float mn = fmaxf(m1, pm);
                const float sc = __builtin_amdgcn_exp2f(m1 - mn);
                m1 = mn; l1 *= sc;
                #pragma unroll
                for (int db = 0; db < 4; ++db)
                    #pragma unroll
                    for (int j = 0; j < 4; ++j) acc1[db][j] *= sc;
            }
            float rsum = 0.f;
            #pragma unroll
            for (int cb = 0; cb < 4; ++cb)
                #pragma unroll
                for (int j = 0; j < 4; ++j) {
                    const float pv = __builtin_amdgcn_exp2f(sacc[cb][j] - m1);
                    sacc[cb][j] = pv;
                    rsum += pv;
                }
            rsum += __shfl_xor(rsum, 16);
            rsum += __shfl_xor(rsum, 32);
            l1 += rsum;
            bf16x8 pf0, pf1;
            #pragma unroll
            for (int i = 0; i < 8; ++i) {
                pf0[i] = (bf16)sacc[i >> 2][i & 3];
                pf1[i] = (bf16)sacc[2 + (i >> 2)][i & 3];
            }
            #pragma unroll
            for (int db = 0; db < 4; ++db) acc1[db] = MFMA16(vf[0][db], pf0, acc1[db]);
            #pragma unroll
            for (int db = 0; db < 4; ++db) acc1[db] = MFMA16(vf[1][db], pf1, acc1[db]);
        }
        asm volatile("" ::: "memory");
        __builtin_amdgcn_s_barrier();            // WAR: slot reused by stage(kt+3)
        asm volatile("" ::: "memory");
    }

    // ---- epilogue: lane owns q-col l16; d = 16db+4g+j ----
    {
        const float inv = 1.f / l2;
        const int t = (q2b << 6) + qloc;
        #pragma unroll
        for (int db = 0; db < 4; ++db) {
            bf16x4 o;
            #pragma unroll
            for (int j = 0; j < 4; ++j) o[j] = (bf16)(acc2[db][j] * inv);
            *(bf16x4*)(att + (((size_t)b << 10) + t) * 1024 + (h << 6) + (db << 4) + (g << 2)) = o;
        }
    }
    {
        const float inv = 1.f / l1;
        const int t = (q1b << 6) + qloc;
        #pragma unroll
        for (int db = 0; db < 4; ++db) {
            bf16x4 o;
            #pragma unroll
            for (int j = 0; j < 4; ++j) o[j] = (bf16)(acc1[db][j] * inv);
            *(bf16x4*)(att + (((size_t)b << 10) + t) * 1024 + (h << 6) + (db << 4) + (g << 2)) = o;
        }
    }
}

extern "C" void kernel_launch(void* const* d_in, const int* in_sizes, int n_in,
                              void* d_out, int out_size, void* d_ws, size_t ws_size,
                              hipStream_t stream)
{
    const float* x      = (const float*)d_in[0];
    const float* w_attn = (const float*)d_in[1];
    const float* b_attn = (const float*)d_in[2];
    const float* w_proj = (const float*)d_in[3];
    const float* b_proj = (const float*)d_in[4];
    float* out = (float*)d_out;

    // workspace layout (bf16 elems)
    bf16* xb  = (bf16*)d_ws;                        // [4096][1024]
    bf16* wT  = xb  + (size_t)4096 * 1024;          // [3072][1024]
    bf16* wpT = wT  + (size_t)3072 * 1024;          // [1024][1024]
    bf16* qw  = wpT + (size_t)1024 * 1024;          // [64 bh][1024 t][64 d]
    bf16* kw  = qw  + (size_t)64 * 1024 * 64;       // [64 bh][1024 t][64 d]
    bf16* vw  = kw  + (size_t)64 * 1024 * 64;       // [64 bh][64 d][1024 t']
    bf16* aw  = vw  + (size_t)64 * 1024 * 64;       // [4096][1024]

    prep_k<<<3072, 256, 0, stream>>>(x, xb, w_attn, wT, w_proj, wpT);

    gemm_bt<0><<<768, 256, 0, stream>>>(xb, wT, b_attn, qw, kw, vw, nullptr);
    attn_k<<<dim3(64, 8), 256, 0, stream>>>(qw, kw, vw, aw);
    gemm_bt<1><<<512, 256, 0, stream>>>(aw, wpT, b_proj, nullptr, nullptr, nullptr, out);
}

// Round 15
// 81.912 us; speedup vs baseline: 1.0348x; 1.0348x over previous
//
#include <hip/hip_runtime.h>

typedef __bf16 bf16;
typedef float f32x4 __attribute__((ext_vector_type(4)));
typedef bf16 bf16x4 __attribute__((ext_vector_type(4)));
typedef bf16 bf16x8 __attribute__((ext_vector_type(8)));

#define MFMA16(a, b, c) __builtin_amdgcn_mfma_f32_16x16x32_bf16((a), (b), (c), 0, 0, 0)

__device__ __forceinline__ f32x4 zero4() {
    f32x4 z; z[0] = 0.f; z[1] = 0.f; z[2] = 0.f; z[3] = 0.f; return z;
}
__device__ __forceinline__ float max3f(float a, float b, float c) {
    return fmaxf(fmaxf(a, b), c);      // fuses to v_max3_f32
}
// async global -> LDS, 16B/lane. LDS dest = wave-uniform base + lane*16.
__device__ __forceinline__ void gl_lds16(const bf16* g, bf16* l) {
    __builtin_amdgcn_global_load_lds(
        (const __attribute__((address_space(1))) void*)g,
        (__attribute__((address_space(3))) void*)l, 16, 0, 0);
}

// ---------------- fused prep: x f32->bf16 | transpose w_attn | transpose w_proj ----------------
__global__ __launch_bounds__(256)
void prep_k(const float* __restrict__ x, bf16* __restrict__ xb,
            const float* __restrict__ w_attn, bf16* __restrict__ wT,
            const float* __restrict__ w_proj, bf16* __restrict__ wpT)
{
    __shared__ bf16 Ls[64][72];
    const int blk = blockIdx.x;
    const int tid = threadIdx.x;

    if (blk < 2048) {
        const int i = (blk * 256 + tid) * 8;
        const float4 a = *(const float4*)(x + i);
        const float4 b = *(const float4*)(x + i + 4);
        bf16x8 o;
        o[0] = (bf16)a.x; o[1] = (bf16)a.y; o[2] = (bf16)a.z; o[3] = (bf16)a.w;
        o[4] = (bf16)b.x; o[5] = (bf16)b.y; o[6] = (bf16)b.z; o[7] = (bf16)b.w;
        *(bf16x8*)(xb + i) = o;
        return;
    }
    const float* src;
    bf16* dst;
    int K, N, bx, by;
    if (blk < 2816) {
        const int r = blk - 2048;
        src = w_attn; dst = wT; K = 1024; N = 3072;
        bx = r % 48; by = r / 48;
    } else {
        const int r = blk - 2816;
        src = w_proj; dst = wpT; K = 1024; N = 1024;
        bx = r & 15; by = r >> 4;
    }
    const int k0 = by << 6;
    const int n0 = bx << 6;
    #pragma unroll
    for (int it = 0; it < 4; ++it) {
        const int lin = (it << 10) + (tid << 2);
        const int r = lin >> 6, c = lin & 63;
        const float4 v = *(const float4*)(src + (size_t)(k0 + r) * N + n0 + c);
        bf16x4 o; o[0] = (bf16)v.x; o[1] = (bf16)v.y; o[2] = (bf16)v.z; o[3] = (bf16)v.w;
        *(bf16x4*)&Ls[r][c] = o;
    }
    __syncthreads();
    #pragma unroll
    for (int it = 0; it < 2; ++it) {
        const int lin = (it << 11) + (tid << 3);
        const int nn = lin >> 6, kk = lin & 63;
        bf16x8 o;
        #pragma unroll
        for (int j = 0; j < 8; ++j) o[j] = Ls[kk + j][nn];
        *(bf16x8*)(dst + (size_t)(n0 + nn) * K + k0 + kk) = o;
    }
}

// ---------------- bf16 GEMM, B^T input, depth-2 counted-vmcnt pipeline, BK=32 ----------------
// Fully unrolled K-loop: buffer slots, prefetch guards, and global offsets are static.
// MODE 0 (BN=128): scatter q/k packed [bh][t][d] + v transposed+t-permuted [bh][d][t'] via LDS-pack
// MODE 1 (BN=64):  f32 out[M][N] + bias, direct stores
template <int MODE>
__global__ __launch_bounds__(256)
void gemm_bt(const bf16* __restrict__ A, const bf16* __restrict__ Bt,
             const float* __restrict__ bias,
             bf16* __restrict__ qw, bf16* __restrict__ kw, bf16* __restrict__ vw,
             float* __restrict__ outf)
{
    constexpr int BK = 32;
    constexpr int BN = (MODE == 0) ? 128 : 64;
    constexpr int K  = 1024;
    constexpr int N  = (MODE == 0) ? 3072 : 1024;
    constexpr int MF = (MODE == 0) ? 4 : 2;
    constexpr int NF = 4;
    constexpr int AE = 128 * BK;
    constexpr int BE = BN * BK;
    constexpr int nk = K / BK;                   // 32

    __shared__ __align__(16) bf16 smem[3 * (AE + BE)];
    bf16* const Asb = smem;
    bf16* const Bsb = smem + 3 * AE;

    const int tid  = threadIdx.x;
    const int lane = tid & 63;
    const int wid  = tid >> 6;
    const int l16  = lane & 15;
    const int g    = lane >> 4;
    const int wrb  = (MODE == 0) ? ((wid >> 1) << 6) : (wid << 5);
    const int wcb  = (MODE == 0) ? ((wid & 1) << 6) : 0;

    // ---- XCD-aware bijective 2-D swizzle (1-D grid) ----
    const int p   = blockIdx.x;
    const int xcd = p & 7;
    const int r   = p >> 3;
    int by, bx;
    if (MODE == 0) { by = ((xcd >> 1) << 3) + r / 12; bx = (xcd & 1) * 12 + r % 12; }
    else           { by = ((xcd >> 1) << 3) + (r >> 3); bx = ((xcd & 1) << 3) + (r & 7); }
    const int m0 = by << 7;
    const int n0 = bx * BN;

    // staging: 16 rows x 64B per instr; source chunk XOR-preswizzled by (row>>1)&3
    const int srow = lane >> 2;
    const int schk = lane & 3;
    const int rA0 = (wid << 5) + srow;
    const int rA1 = rA0 + 16;
    const int rB0 = wid * (BN / 4) + srow;
    const int rB1 = rB0 + 16;
    const bf16* const pa0 = A  + (size_t)(m0 + rA0) * K + ((schk ^ ((rA0 >> 1) & 3)) << 3);
    const bf16* const pa1 = A  + (size_t)(m0 + rA1) * K + ((schk ^ ((rA1 >> 1) & 3)) << 3);
    const bf16* const pb0 = Bt + (size_t)(n0 + rB0) * K + ((schk ^ ((rB0 >> 1) & 3)) << 3);
    const bf16* const pb1 = Bt + (size_t)(n0 + rB1) * K + ((schk ^ ((rB1 >> 1) & 3)) << 3);
    const int dA0 = (wid << 5) * BK, dA1 = dA0 + 16 * BK;
    const int dB0 = (wid * (BN / 4)) * BK, dB1 = dB0 + 16 * BK;

    // fragment read offsets (elems), swizzle-matched
    int offA[MF], offB[NF];
    #pragma unroll
    for (int mf = 0; mf < MF; ++mf) {
        const int rr = wrb + (mf << 4) + l16;
        offA[mf] = rr * BK + ((g ^ ((rr >> 1) & 3)) << 3);
    }
    #pragma unroll
    for (int nf = 0; nf < NF; ++nf) {
        const int rr = wcb + (nf << 4) + l16;
        offB[nf] = rr * BK + ((g ^ ((rr >> 1) & 3)) << 3);
    }

    f32x4 acc[MF][NF];
    #pragma unroll
    for (int i = 0; i < MF; ++i)
        #pragma unroll
        for (int j = 0; j < NF; ++j) acc[i][j] = zero4();

    auto issue = [&](int t, int s) {
        bf16* const ab = Asb + s * AE;
        bf16* const bb = Bsb + s * BE;
        gl_lds16(pa0 + t * BK, ab + dA0);
        gl_lds16(pa1 + t * BK, ab + dA1);
        gl_lds16(pb0 + t * BK, bb + dB0);
        if constexpr (MODE == 0) gl_lds16(pb1 + t * BK, bb + dB1);
    };

    issue(0, 0);
    issue(1, 1);

    #pragma unroll
    for (int kt = 0; kt < nk; ++kt) {
        if (kt == nk - 1) {
            asm volatile("s_waitcnt vmcnt(0)" ::: "memory");
        } else {
            if constexpr (MODE == 0) asm volatile("s_waitcnt vmcnt(4)" ::: "memory");
            else                     asm volatile("s_waitcnt vmcnt(3)" ::: "memory");
        }
        __builtin_amdgcn_s_barrier();            // tile kt staged for all waves
        if (kt + 2 < nk) issue(kt + 2, (kt + 2) % 3);
        const bf16* const ac = Asb + (kt % 3) * AE;
        const bf16* const bc = Bsb + (kt % 3) * BE;
        bf16x8 af[MF], bfr[NF];
        #pragma unroll
        for (int mf = 0; mf < MF; ++mf) af[mf] = *(const bf16x8*)&ac[offA[mf]];
        #pragma unroll
        for (int nf = 0; nf < NF; ++nf) bfr[nf] = *(const bf16x8*)&bc[offB[nf]];
        __builtin_amdgcn_s_setprio(1);
        #pragma unroll
        for (int mf = 0; mf < MF; ++mf)
            #pragma unroll
            for (int nf = 0; nf < NF; ++nf)
                acc[mf][nf] = MFMA16(af[mf], bfr[nf], acc[mf][nf]);
        __builtin_amdgcn_s_setprio(0);
    }
    __syncthreads();                             // reads done before smem reuse

    if (MODE == 0) {
        // ---- LDS-pack epilogue: 128x128 bf16 tile reusing smem ----
        bf16* const Es = smem;
        const int bq  = m0 >> 10;
        const int tb  = m0 & 1023;
        const int hh0 = (n0 & 1023) >> 6;
        const bool isV = (n0 >= 2048);
        if (isV) {
            #pragma unroll
            for (int mf = 0; mf < MF; ++mf)
                #pragma unroll
                for (int nf = 0; nf < NF; ++nf) {
                    const int nn = wcb + (nf << 4) + l16;
                    const float bs = bias[n0 + nn];
                    bf16x4 pq;
                    #pragma unroll
                    for (int j = 0; j < 4; ++j) pq[j] = (bf16)(acc[mf][nf][j] + bs);
                    // transposed + PV-kmap permuted: t = 32s+16h+4g'+j -> pos 32s+8g'+4h+j
                    const int m = wrb + (mf << 4) + (g << 2);
                    const int pp = ((m >> 5) << 5) + (((m >> 2) & 3) << 3) + (((m >> 4) & 1) << 2);
                    *(bf16x4*)&Es[nn * 128 + pp] = pq;
                }
        } else {
            #pragma unroll
            for (int mf = 0; mf < MF; ++mf)
                #pragma unroll
                for (int nf = 0; nf < NF; ++nf) {
                    const int nn = wcb + (nf << 4) + l16;
                    const float bs = bias[n0 + nn];
                    #pragma unroll
                    for (int j = 0; j < 4; ++j) {
                        const int mm = wrb + (mf << 4) + (g << 2) + j;
                        Es[mm * 128 + nn] = (bf16)(acc[mf][nf][j] + bs);
                    }
                }
        }
        __syncthreads();
        #pragma unroll
        for (int it = 0; it < 8; ++it) {
            const int idx = (it << 8) + tid;
            const int row = idx >> 4, ch = idx & 15;
            const bf16x8 v = *(const bf16x8*)&Es[row * 128 + (ch << 3)];
            if (isV) {
                const int dd = row & 63, hh = hh0 + (row >> 6);
                *(bf16x8*)(vw + ((size_t)((bq << 4) + hh) << 16) + ((size_t)dd << 10)
                           + tb + (ch << 3)) = v;
            } else {
                const int t = tb + row;
                const int cc = ch << 3;
                const int hh = hh0 + (cc >> 6);
                bf16* const dst = (n0 < 1024) ? qw : kw;
                *(bf16x8*)(dst + ((size_t)((bq << 4) + hh) << 16) + ((size_t)t << 6)
                           + (cc & 63)) = v;
            }
        }
    } else {
        #pragma unroll
        for (int mf = 0; mf < MF; ++mf)
            #pragma unroll
            for (int nf = 0; nf < NF; ++nf) {
                const int ng = n0 + wcb + (nf << 4) + l16;
                const float bs = bias[ng];
                #pragma unroll
                for (int j = 0; j < 4; ++j) {
                    const int mg = m0 + wrb + (mf << 4) + (g << 2) + j;
                    outf[(size_t)mg * N + ng] = acc[mf][nf][j] + bs;
                }
            }
    }
}

// ---------------- flash attention: swapped-QK^T, one q-block per block ----------------
// Q,K [bh][1024][64]; Vt [bh][64][1024 t-permuted]; out att [4096][1024] bf16.
// grid 1024 (1-D): p -> xcd = p&7, i = p>>3; bh = (xcd<<3)+(i&7) (same-head blocks on one
// XCD; under within-XCD round-robin each CU sees a single bh), qb = perm(i>>3) with
// perm{15-q, 8+q, 7-q, q} so any stride-32 window of 4 blocks sums to 34 kv-tiles (balanced).
// 4 blocks/CU (32KB LDS) = 4 waves/SIMD for latency hiding. Depth-1 counted-vmcnt dbuf.
__global__ __launch_bounds__(256)
void attn_k(const bf16* __restrict__ Qp, const bf16* __restrict__ Kp,
            const bf16* __restrict__ Vt, bf16* __restrict__ att)
{
    __shared__ __align__(16) bf16 Kl0[4096], Kl1[4096];
    __shared__ __align__(16) bf16 Vl0[4096], Vl1[4096];

    const int p   = blockIdx.x;         // 0..1023
    const int xcd = p & 7;
    const int i   = p >> 3;             // 0..127
    const int bh  = (xcd << 3) + (i & 7);
    const int iq  = i >> 3;             // 0..15
    const int a   = iq >> 2, qs = iq & 3;
    const int qb  = (a == 0) ? (15 - qs) : (a == 1) ? (8 + qs)
                  : (a == 2) ? (7 - qs) : qs;
    const int b   = bh >> 4, h = bh & 15;

    const int tid  = threadIdx.x;
    const int lane = tid & 63;
    const int wid  = tid >> 6;
    const int g    = lane >> 4;
    const int l16  = lane & 15;
    const int g8   = g << 3;

    const size_t hb = (size_t)bh << 16;
    const bf16* Qh = Qp + hb;
    const bf16* Kh = Kp + hb;
    const bf16* Vh = Vt + hb;

    // staging: 8 rows x 128B per instr; source chunk XOR-preswizzled by row&7
    const int srow = lane >> 3;
    const int sswz = ((lane & 7) ^ srow) << 3;
    const int kr0  = (wid << 4) + srow;
    const int kr1  = kr0 + 8;
    const int dst0 = (wid << 4) << 6;
    const int dst1 = ((wid << 4) + 8) << 6;

    // fragment read offsets (elems), swizzle-matched; rows = kv (K) or d (V^T)
    int offKV[2][4];
    #pragma unroll
    for (int ks = 0; ks < 2; ++ks)
        #pragma unroll
        for (int cb = 0; cb < 4; ++cb) {
            const int r = (cb << 4) + l16;
            offKV[ks][cb] = (r << 6) + (((((ks << 2) + g)) ^ (r & 7)) << 3);
        }

    const float QSCALE = 0.125f * 1.44269504f;
    const int qloc = (wid << 4) + l16;
    const int q0 = qb << 6;

    // hoist Q fragments, pre-scaled
    const bf16* qp = Qh + ((size_t)(q0 + qloc) << 6) + g8;
    bf16x8 qf0 = *(const bf16x8*)qp, qf1 = *(const bf16x8*)(qp + 32);
    #pragma unroll
    for (int e = 0; e < 8; ++e) {
        qf0[e] = (bf16)(QSCALE * (float)qf0[e]);
        qf1[e] = (bf16)(QSCALE * (float)qf1[e]);
    }

    f32x4 acc_o[4];
    float m_r = -1e30f, l_r = 0.f;
    #pragma unroll
    for (int i2 = 0; i2 < 4; ++i2) acc_o[i2] = zero4();

    auto stage = [&](int t, bf16* Kn, bf16* Vn) {
        const int kv = t << 6;
        gl_lds16(Kh + ((size_t)(kv + kr0) << 6) + sswz, Kn + dst0);
        gl_lds16(Kh + ((size_t)(kv + kr1) << 6) + sswz, Kn + dst1);
        gl_lds16(Vh + ((size_t)kr0 << 10) + kv + sswz, Vn + dst0);
        gl_lds16(Vh + ((size_t)kr1 << 10) + kv + sswz, Vn + dst1);
    };

    stage(0, Kl0, Vl0);

    for (int kt = 0; kt <= qb; ++kt) {
        const bool odd = kt & 1;
        if (kt < qb) {                           // prefetch kt+1 into the other buffer
            stage(kt + 1, odd ? Kl0 : Kl1, odd ? Vl0 : Vl1);
            asm volatile("s_waitcnt vmcnt(4)" ::: "memory");   // tile kt's 4 loads done
        } else {
            asm volatile("s_waitcnt vmcnt(0)" ::: "memory");
        }
        __builtin_amdgcn_s_barrier();            // all waves' tile-kt stage visible
        const bf16* Kc = odd ? Kl1 : Kl0;
        const bf16* Vc = odd ? Vl1 : Vl0;

        // preload K and V^T fragments
        bf16x8 kf[2][4], vf[2][4];
        #pragma unroll
        for (int ks = 0; ks < 2; ++ks)
            #pragma unroll
            for (int cb = 0; cb < 4; ++cb) {
                kf[ks][cb] = *(const bf16x8*)&Kc[offKV[ks][cb]];
                vf[ks][cb] = *(const bf16x8*)&Vc[offKV[ks][cb]];
            }

        // ---- S^T = mfma(K, Q): sacc[cb][j] = S~[kv=16cb+4g+j][q=l16] ----
        f32x4 sacc[4];
        #pragma unroll
        for (int cb = 0; cb < 4; ++cb) sacc[cb] = zero4();
        #pragma unroll
        for (int cb = 0; cb < 4; ++cb) sacc[cb] = MFMA16(kf[0][cb], qf0, sacc[cb]);
        #pragma unroll
        for (int cb = 0; cb < 4; ++cb) sacc[cb] = MFMA16(kf[1][cb], qf1, sacc[cb]);
        if (kt == qb) {                          // causal mask on diagonal tile
            #pragma unroll
            for (int cb = 0; cb < 4; ++cb)
                #pragma unroll
                for (int j = 0; j < 4; ++j)
                    if (((cb << 4) + (g << 2) + j) > qloc) sacc[cb][j] = -1e30f;
        }
        // ---- online softmax, exp2 domain, per-lane scalar, defer-max THR=8 ----
        const float t0 = max3f(sacc[0][0], sacc[0][1], sacc[0][2]);
        const float t1 = max3f(sacc[0][3], sacc[1][0], sacc[1][1]);
        const float t2 = max3f(sacc[1][2], sacc[1][3], sacc[2][0]);
        const float t3 = max3f(sacc[2][1], sacc[2][2], sacc[2][3]);
        const float t4 = max3f(sacc[3][0], sacc[3][1], sacc[3][2]);
        float pm = fmaxf(max3f(t0, t1, t2), max3f(t3, t4, sacc[3][3]));
        pm = fmaxf(pm, __shfl_xor(pm, 16));
        pm = fmaxf(pm, __shfl_xor(pm, 32));
        if (__any(pm > m_r + 8.f)) {
            const float mn = fmaxf(m_r, pm);
            const float sc = __builtin_amdgcn_exp2f(m_r - mn);
            m_r = mn; l_r *= sc;
            #pragma unroll
            for (int db = 0; db < 4; ++db)
                #pragma unroll
                for (int j = 0; j < 4; ++j) acc_o[db][j] *= sc;
        }
        float rsum = 0.f;
        #pragma unroll
        for (int cb = 0; cb < 4; ++cb)
            #pragma unroll
            for (int j = 0; j < 4; ++j) {
                const float pv = __builtin_amdgcn_exp2f(sacc[cb][j] - m_r);
                sacc[cb][j] = pv;
                rsum += pv;
            }
        rsum += __shfl_xor(rsum, 16);
        rsum += __shfl_xor(rsum, 32);
        l_r += rsum;
        // ---- P^T fragments in-register (kv = 32ks+16h+4g+j at elem i=4h+j) ----
        bf16x8 pf0, pf1;
        #pragma unroll
        for (int e = 0; e < 8; ++e) {
            pf0[e] = (bf16)sacc[e >> 2][e & 3];
            pf1[e] = (bf16)sacc[2 + (e >> 2)][e & 3];
        }
        // ---- O^T += V^T P^T ----
        #pragma unroll
        for (int db = 0; db < 4; ++db) acc_o[db] = MFMA16(vf[0][db], pf0, acc_o[db]);
        #pragma unroll
        for (int db = 0; db < 4; ++db) acc_o[db] = MFMA16(vf[1][db], pf1, acc_o[db]);

        asm volatile("" ::: "memory");
        __builtin_amdgcn_s_barrier();            // WAR: buffer restaged next iteration
        asm volatile("" ::: "memory");
    }

    // ---- epilogue: lane owns q-col l16 -> t fixed; d = 16db+4g+j ----
    const float inv = 1.f / l_r;
    const int t = q0 + qloc;
    #pragma unroll
    for (int db = 0; db < 4; ++db) {
        bf16x4 o;
        #pragma unroll
        for (int j = 0; j < 4; ++j) o[j] = (bf16)(acc_o[db][j] * inv);
        *(bf16x4*)(att + (((size_t)b << 10) + t) * 1024 + (h << 6) + (db << 4) + (g << 2)) = o;
    }
}

extern "C" void kernel_launch(void* const* d_in, const int* in_sizes, int n_in,
                              void* d_out, int out_size, void* d_ws, size_t ws_size,
                              hipStream_t stream)
{
    const float* x      = (const float*)d_in[0];
    const float* w_attn = (const float*)d_in[1];
    const float* b_attn = (const float*)d_in[2];
    const float* w_proj = (const float*)d_in[3];
    const float* b_proj = (const float*)d_in[4];
    float* out = (float*)d_out;

    // workspace layout (bf16 elems)
    bf16* xb  = (bf16*)d_ws;                        // [4096][1024]
    bf16* wT  = xb  + (size_t)4096 * 1024;          // [3072][1024]
    bf16* wpT = wT  + (size_t)3072 * 1024;          // [1024][1024]
    bf16* qw  = wpT + (size_t)1024 * 1024;          // [64 bh][1024 t][64 d]
    bf16* kw  = qw  + (size_t)64 * 1024 * 64;       // [64 bh][1024 t][64 d]
    bf16* vw  = kw  + (size_t)64 * 1024 * 64;       // [64 bh][64 d][1024 t']
    bf16* aw  = vw  + (size_t)64 * 1024 * 64;       // [4096][1024]

    prep_k<<<3072, 256, 0, stream>>>(x, xb, w_attn, wT, w_proj, wpT);

    gemm_bt<0><<<768, 256, 0, stream>>>(xb, wT, b_attn, qw, kw, vw, nullptr);
    attn_k<<<1024, 256, 0, stream>>>(qw, kw, vw, aw);
    gemm_bt<1><<<512, 256, 0, stream>>>(aw, wpT, b_proj, nullptr, nullptr, nullptr, out);
}